// Round 5
// baseline (321.982 us; speedup 1.0000x reference)
//
#include <hip/hip_runtime.h>
#include <hip/hip_bf16.h>

typedef __hip_bfloat16 bf16;
typedef __bf16 bfrag __attribute__((ext_vector_type(8)));   // 8 bf16 = 4 VGPRs (MFMA A/B operand)
typedef float f32x4 __attribute__((ext_vector_type(4)));    // MFMA C/D

#define AS1 __attribute__((address_space(1)))
#define AS3 __attribute__((address_space(3)))

static constexpr int Bb = 8, Nn = 4096, Cc = 512, Hh = 8;
static constexpr int Mtok = Bb * Nn;          // 32768
static constexpr int QKVC = 3 * Cc;           // 1536
// ws layout (NEED = 57,147,392 bytes; round 4 proved ws_size >= 59,768,832):
//  xn/g [0, 33554432)          bf16 [32768][512]
//  Gcov [33554432, 41943040)   f32  [8][512][512]
//  Gcvb [41943040, 46137344)   bf16 [8][512][512]
//  T    [46137344, 54525952)   bf16 [8][1024][512]
//  P    [54525952, 55050240)   bf16 [8][8][64][64]
//  wq   [55050240, 56623104)   bf16 [1536][512]
//  wp   [56623104, 57147392)   bf16 [512][512]
static constexpr size_t WS_NEED = 57147392;

__device__ __forceinline__ void gl_lds16(const void* g, void* l) {
  __builtin_amdgcn_global_load_lds((const AS1 void*)g, (AS3 void*)l, 16, 0, 0);
}
__device__ __forceinline__ float gelu_exact(float x) {
  return 0.5f * x * (1.0f + erff(x * 0.70710678118654752f));
}

// ---------------- diagnostic fill (fp32 output) ----------------
__global__ __launch_bounds__(256) void fill_f32(float* o, float val, int n) {
  int i = blockIdx.x * 256 + threadIdx.x;
  if (i < n) o[i] = val;
}

// ---------------- fp32 -> bf16 conversion ----------------
__global__ __launch_bounds__(256) void cvt_f32_bf16(const float* __restrict__ a,
                                                    bf16* __restrict__ o, int n) {
  int i = (blockIdx.x * 256 + threadIdx.x) * 8;
  if (i + 8 <= n) {
    float f[8];
    *(float4*)f       = *(const float4*)(a + i);
    *(float4*)(f + 4) = *(const float4*)(a + i + 4);
    bf16 v[8];
#pragma unroll
    for (int j = 0; j < 8; ++j) v[j] = __float2bfloat16(f[j]);
    *(uint4*)(o + i) = *(uint4*)v;
  }
}

// ---------------- LayerNorm (one wave per token), fp32 in -> bf16 out ----------------
__global__ __launch_bounds__(256) void ln_kernel(const float* __restrict__ x,
                                                 const float* __restrict__ gw,
                                                 const float* __restrict__ bw,
                                                 bf16* __restrict__ xn) {
  int tok  = blockIdx.x * 4 + (threadIdx.x >> 6);
  int lane = threadIdx.x & 63;
  const float* xr = x + (size_t)tok * Cc + lane * 8;
  float f[8];
  *(float4*)f       = *(const float4*)xr;
  *(float4*)(f + 4) = *(const float4*)(xr + 4);
  float s = 0.f;
#pragma unroll
  for (int j = 0; j < 8; ++j) s += f[j];
#pragma unroll
  for (int m = 32; m; m >>= 1) s += __shfl_xor(s, m);
  float mu = s * (1.0f / 512.0f);
  float q = 0.f;
#pragma unroll
  for (int j = 0; j < 8; ++j) { float d = f[j] - mu; q += d * d; }
#pragma unroll
  for (int m = 32; m; m >>= 1) q += __shfl_xor(q, m);
  float rstd = rsqrtf(q * (1.0f / 512.0f) + 1e-5f);
  bf16 o[8];
#pragma unroll
  for (int j = 0; j < 8; ++j)
    o[j] = __float2bfloat16((f[j] - mu) * rstd * gw[lane * 8 + j] + bw[lane * 8 + j]);
  *(uint4*)(xn + (size_t)tok * Cc + lane * 8) = *(uint4*)o;
}

// ------------- GEMM C[M,N] = A[M,K] @ B[N,K]^T, bf16 in, bf16 OR fp32 out, batched -------------
template <typename TC>
__global__ __launch_bounds__(256) void gemm_bt(const bf16* __restrict__ A,
                                               const bf16* __restrict__ B,
                                               TC* __restrict__ C,
                                               int M, int N, int K,
                                               const float* __restrict__ bias,
                                               long sA_z, long sB_z, long sC_z) {
  A += (size_t)blockIdx.z * sA_z;
  B += (size_t)blockIdx.z * sB_z;
  C += (size_t)blockIdx.z * sC_z;
  __shared__ __align__(16) bf16 smem[16384];   // sA[128][64] | sB[128][64]; reused as ct[128][128]
  bf16* sA = smem;
  bf16* sB = smem + 8192;
  int t = threadIdx.x, w = t >> 6, lane = t & 63, fr = lane & 15, quad = lane >> 4;
  int n0 = blockIdx.x * 128, m0 = blockIdx.y * 128;
  int wm = (w >> 1) * 64, wn = (w & 1) * 64;
  f32x4 acc[4][4] = {};

  for (int k0 = 0; k0 < K; k0 += 64) {
    __syncthreads();
#pragma unroll
    for (int c2 = 0; c2 < 4; ++c2) {
      int c = w * 4 + c2;                // 1KB chunk id, 0..15
      int row = c * 8 + (lane >> 3);     // 0..127
      int ke  = (lane & 7) * 8;
      gl_lds16(A + (size_t)(m0 + row) * K + k0 + ke, (char*)sA + c * 1024);
      gl_lds16(B + (size_t)(n0 + row) * K + k0 + ke, (char*)sB + c * 1024);
    }
    __syncthreads();
#pragma unroll
    for (int kk = 0; kk < 64; kk += 32) {
      bfrag af[4], bg[4];
#pragma unroll
      for (int i = 0; i < 4; ++i) af[i] = *(const bfrag*)(sA + (wm + i * 16 + fr) * 64 + kk + quad * 8);
#pragma unroll
      for (int j = 0; j < 4; ++j) bg[j] = *(const bfrag*)(sB + (wn + j * 16 + fr) * 64 + kk + quad * 8);
#pragma unroll
      for (int i = 0; i < 4; ++i)
#pragma unroll
        for (int j = 0; j < 4; ++j)
          acc[i][j] = __builtin_amdgcn_mfma_f32_16x16x32_bf16(af[i], bg[j], acc[i][j], 0, 0, 0);
    }
  }

  if constexpr (__is_same(TC, float)) {
    // direct fp32 stores from C-fragment layout (col=fr, row=quad*4+r)
#pragma unroll
    for (int j = 0; j < 4; ++j) {
      float bj = bias ? bias[n0 + wn + j * 16 + fr] : 0.0f;
#pragma unroll
      for (int i = 0; i < 4; ++i)
#pragma unroll
        for (int r = 0; r < 4; ++r)
          C[(size_t)(m0 + wm + i * 16 + quad * 4 + r) * N + n0 + wn + j * 16 + fr] =
              acc[i][j][r] + bj;
    }
  } else {
    __syncthreads();
    bf16* ct = smem;                      // [128][128]
#pragma unroll
    for (int j = 0; j < 4; ++j) {
      float bj = bias ? bias[n0 + wn + j * 16 + fr] : 0.0f;
#pragma unroll
      for (int i = 0; i < 4; ++i)
#pragma unroll
        for (int r = 0; r < 4; ++r)
          ct[(wm + i * 16 + quad * 4 + r) * 128 + wn + j * 16 + fr] =
              __float2bfloat16(acc[i][j][r] + bj);
    }
    __syncthreads();
#pragma unroll
    for (int r8 = 0; r8 < 8; ++r8) {
      int row = r8 * 16 + (t >> 4);
      int ce  = (t & 15) * 8;
      *(uint4*)(C + (size_t)(m0 + row) * N + n0 + ce) = *(const uint4*)(smem + row * 128 + ce);
    }
  }
}

// ---- Gcov[b] += Xb^T Xb (split-K over tokens, XOR-swizzled LDS transpose, fp32 atomics) ----
__global__ __launch_bounds__(256) void xtx(const bf16* __restrict__ xn,
                                           float* __restrict__ Gcov) {
  int tile = blockIdx.x;           // 0..15 -> (m0,n0)
  int split = blockIdx.y;          // 0..7, 512 tokens each
  int b = blockIdx.z;
  int m0 = (tile >> 2) * 128, n0 = (tile & 3) * 128;
  int t = threadIdx.x, w = t >> 6, lane = t & 63, fr = lane & 15, quad = lane >> 4;
  int wm = (w >> 1) * 64, wn = (w & 1) * 64;
  __shared__ __align__(16) bf16 sA[8192], sB[8192];   // [128 ch][64 tok], token XOR-swizzled
  f32x4 acc[4][4] = {};
  const bf16* xb = xn + ((size_t)b * Nn + split * 512) * Cc;
  int ch0 = (t & 15) * 8;
  int sw  = (t & 7) << 3;
  for (int kc = 0; kc < 8; ++kc) {
    __syncthreads();
#pragma unroll
    for (int it = 0; it < 4; ++it) {
      int tk  = it * 16 + (t >> 4);
      int tks = tk ^ sw;
      bf16 va[8]; *(uint4*)va = *(const uint4*)(xb + (size_t)(kc * 64 + tk) * Cc + m0 + ch0);
      bf16 vb[8]; *(uint4*)vb = *(const uint4*)(xb + (size_t)(kc * 64 + tk) * Cc + n0 + ch0);
#pragma unroll
      for (int j = 0; j < 8; ++j) {
        sA[(ch0 + j) * 64 + tks] = va[j];
        sB[(ch0 + j) * 64 + tks] = vb[j];
      }
    }
    __syncthreads();
#pragma unroll
    for (int s = 0; s < 2; ++s) {
      bfrag af[4], bg[4];
#pragma unroll
      for (int i = 0; i < 4; ++i) {
        int ch = wm + i * 16 + fr;
        int blk = (s * 4 + quad) ^ ((ch >> 3) & 7);
        af[i] = *(const bfrag*)(sA + ch * 64 + blk * 8);
      }
#pragma unroll
      for (int j = 0; j < 4; ++j) {
        int ch = wn + j * 16 + fr;
        int blk = (s * 4 + quad) ^ ((ch >> 3) & 7);
        bg[j] = *(const bfrag*)(sB + ch * 64 + blk * 8);
      }
#pragma unroll
      for (int i = 0; i < 4; ++i)
#pragma unroll
        for (int j = 0; j < 4; ++j)
          acc[i][j] = __builtin_amdgcn_mfma_f32_16x16x32_bf16(af[i], bg[j], acc[i][j], 0, 0, 0);
    }
  }
  float* gb = Gcov + (size_t)b * Cc * Cc;
#pragma unroll
  for (int i = 0; i < 4; ++i)
#pragma unroll
    for (int j = 0; j < 4; ++j)
#pragma unroll
      for (int r = 0; r < 4; ++r)
        atomicAdd(&gb[(size_t)(m0 + wm + i * 16 + quad * 4 + r) * Cc + n0 + wn + j * 16 + fr],
                  acc[i][j][r]);
}

// ---- per (b,h): Gram = T_q @ Wk^T (MFMA, K=512), norms via row-dots, softmax -> P bf16 ----
__global__ __launch_bounds__(256) void gram_softmax(const bf16* __restrict__ T,
                                                    const bf16* __restrict__ wq,
                                                    const float* __restrict__ temp,
                                                    bf16* __restrict__ P) {
  int h = blockIdx.x, b = blockIdx.y;
  int t = threadIdx.x, w = t >> 6, lane = t & 63, fr = lane & 15, quad = lane >> 4;
  const bf16* Tq = T + (size_t)b * 1024 * 512 + (size_t)(h * 64) * 512;
  const bf16* Tk = T + (size_t)b * 1024 * 512 + (size_t)(512 + h * 64) * 512;
  const bf16* Wqh = wq + (size_t)(h * 64) * 512;
  const bf16* Wkh = wq + (size_t)(512 + h * 64) * 512;
  f32x4 acc[4][4] = {};
#pragma unroll
  for (int s = 0; s < 4; ++s) {
    int kb = w * 128 + s * 32 + quad * 8;
    bfrag af[4], bg[4];
#pragma unroll
    for (int i = 0; i < 4; ++i) af[i] = *(const bfrag*)(Tq + (size_t)(i * 16 + fr) * 512 + kb);
#pragma unroll
    for (int j = 0; j < 4; ++j) bg[j] = *(const bfrag*)(Wkh + (size_t)(j * 16 + fr) * 512 + kb);
#pragma unroll
    for (int i = 0; i < 4; ++i)
#pragma unroll
      for (int j = 0; j < 4; ++j)
        acc[i][j] = __builtin_amdgcn_mfma_f32_16x16x32_bf16(af[i], bg[j], acc[i][j], 0, 0, 0);
  }
  __shared__ float parts[4 * 4096];
  __shared__ float nrm[2][4][64];
  __shared__ float nqk[2][64];
#pragma unroll
  for (int i = 0; i < 4; ++i)
#pragma unroll
    for (int j = 0; j < 4; ++j)
#pragma unroll
      for (int r = 0; r < 4; ++r)
        parts[w * 4096 + (i * 16 + quad * 4 + r) * 64 + j * 16 + fr] = acc[i][j][r];
  {
    int d = t & 63, qtr = t >> 6, c0 = qtr * 128;
    float pq = 0.f, pk = 0.f;
#pragma unroll 4
    for (int cc = 0; cc < 16; ++cc) {
      bf16 a[8], ww[8];
      *(uint4*)a  = *(const uint4*)(Tq + (size_t)d * 512 + c0 + cc * 8);
      *(uint4*)ww = *(const uint4*)(Wqh + (size_t)d * 512 + c0 + cc * 8);
#pragma unroll
      for (int j = 0; j < 8; ++j) pq += __bfloat162float(a[j]) * __bfloat162float(ww[j]);
      *(uint4*)a  = *(const uint4*)(Tk + (size_t)d * 512 + c0 + cc * 8);
      *(uint4*)ww = *(const uint4*)(Wkh + (size_t)d * 512 + c0 + cc * 8);
#pragma unroll
      for (int j = 0; j < 8; ++j) pk += __bfloat162float(a[j]) * __bfloat162float(ww[j]);
    }
    nrm[0][qtr][d] = pq;
    nrm[1][qtr][d] = pk;
  }
  __syncthreads();
  if (t < 64) {
    nqk[0][t] = fmaxf(sqrtf(nrm[0][0][t] + nrm[0][1][t] + nrm[0][2][t] + nrm[0][3][t]), 1e-12f);
    nqk[1][t] = fmaxf(sqrtf(nrm[1][0][t] + nrm[1][1][t] + nrm[1][2][t] + nrm[1][3][t]), 1e-12f);
  }
  __syncthreads();
  if (t < 64) {
    int d = t;
    float sc = temp[h] / nqk[0][d];
    float l[64]; float mx = -1e30f;
#pragma unroll
    for (int e = 0; e < 64; ++e) {
      float vsum = parts[d * 64 + e] + parts[4096 + d * 64 + e] +
                   parts[8192 + d * 64 + e] + parts[12288 + d * 64 + e];
      l[e] = vsum * sc / nqk[1][e];
      mx = fmaxf(mx, l[e]);
    }
    float sum = 0.f;
#pragma unroll
    for (int e = 0; e < 64; ++e) { l[e] = expf(l[e] - mx); sum += l[e]; }
    float inv = 1.0f / sum;
    bf16* pr = P + ((size_t)(b * 8 + h) * 64 + d) * 64;
#pragma unroll
    for (int e = 0; e < 64; ++e) pr[e] = __float2bfloat16(l[e] * inv);
  }
}

// ---- out = P @ v, exact GELU, store g[token][C] (bf16) ----
__global__ __launch_bounds__(256) void pv_gelu(const bf16* __restrict__ P,
                                               const bf16* __restrict__ v,
                                               bf16* __restrict__ g) {
  int chunk = blockIdx.x, h = blockIdx.y, b = blockIdx.z;
  int t = threadIdx.x, w = t >> 6, lane = t & 63, fr = lane & 15, quad = lane >> 4;
  const bf16* pb = P + (size_t)(b * 8 + h) * 4096;
  bfrag pf[4][2];
#pragma unroll
  for (int i = 0; i < 4; ++i)
#pragma unroll
    for (int c = 0; c < 2; ++c)
      pf[i][c] = *(const bfrag*)(pb + (i * 16 + fr) * 64 + c * 32 + quad * 8);
#pragma unroll 2
  for (int nt = 0; nt < 8; ++nt) {
    int ntok = chunk * 512 + w * 128 + nt * 16 + fr;
    const bf16* vrow = v + (size_t)(b * Nn + ntok) * Cc + h * 64 + quad * 8;
    bfrag bv0 = *(const bfrag*)(vrow);
    bfrag bv1 = *(const bfrag*)(vrow + 32);
    f32x4 acc[4] = {};
#pragma unroll
    for (int i = 0; i < 4; ++i) {
      acc[i] = __builtin_amdgcn_mfma_f32_16x16x32_bf16(pf[i][0], bv0, acc[i], 0, 0, 0);
      acc[i] = __builtin_amdgcn_mfma_f32_16x16x32_bf16(pf[i][1], bv1, acc[i], 0, 0, 0);
    }
    bf16* grow = g + (size_t)(b * Nn + ntok) * Cc + h * 64;
#pragma unroll
    for (int i = 0; i < 4; ++i) {
      bf16 o[4];
#pragma unroll
      for (int r = 0; r < 4; ++r) o[r] = __float2bfloat16(gelu_exact(acc[i][r]));
      *(uint2*)(grow + i * 16 + quad * 4) = *(uint2*)o;
    }
  }
}

extern "C" void kernel_launch(void* const* d_in, const int* in_sizes, int n_in,
                              void* d_out, int out_size, void* d_ws, size_t ws_size,
                              hipStream_t stream) {
  const float* x      = (const float*)d_in[0];
  const float* ln_g   = (const float*)d_in[1];
  const float* ln_b   = (const float*)d_in[2];
  const float* qkv_w  = (const float*)d_in[3];
  const float* temp   = (const float*)d_in[4];
  const float* proj_w = (const float*)d_in[5];
  const float* proj_b = (const float*)d_in[6];
  float* out = (float*)d_out;                       // fp32 output (reference returns float32)
  char*  ws  = (char*)d_ws;

  // --- runtime guards: silent failure -> measurable absmax signature ---
  const int exp_sizes[7] = {16777216, 512, 512, 786432, 8, 262144, 512};
  bool sizes_ok = (n_in == 7) && (out_size == 16777216);
  if (sizes_ok) for (int i = 0; i < 7; ++i) sizes_ok = sizes_ok && (in_sizes[i] == exp_sizes[i]);
  if (!sizes_ok) {
    fill_f32<<<(16777216 + 255) / 256, 256, 0, stream>>>(out, 500.0f, out_size);
    return;
  }
  if (ws_size < WS_NEED) {
    fill_f32<<<(16777216 + 255) / 256, 256, 0, stream>>>(out, (float)(ws_size >> 20), out_size);
    return;
  }

  bf16*  xn   = (bf16*)ws;                          // reused as g after xtx+vGEMM consume it
  bf16*  g    = (bf16*)ws;
  float* Gcov = (float*)(ws + 33554432);
  bf16*  Gcvb = (bf16*)(ws + 41943040);
  bf16*  T    = (bf16*)(ws + 46137344);
  bf16*  P    = (bf16*)(ws + 54525952);
  bf16*  wq   = (bf16*)(ws + 55050240);
  bf16*  wp   = (bf16*)(ws + 56623104);
  bf16*  v    = (bf16*)d_out;                       // park bf16 v in d_out; dead before final GEMM

  cvt_f32_bf16<<<384, 256, 0, stream>>>(qkv_w, wq, QKVC * Cc);
  cvt_f32_bf16<<<128, 256, 0, stream>>>(proj_w, wp, Cc * Cc);
  hipMemsetAsync(Gcov, 0, (size_t)Bb * Cc * Cc * sizeof(float), stream);
  ln_kernel<<<Mtok / 4, 256, 0, stream>>>(x, ln_g, ln_b, xn);
  // v = xn @ Wv^T (Wv = qkv_w rows 1024..1535)
  gemm_bt<bf16><<<dim3(4, 256, 1), 256, 0, stream>>>(xn, wq + 1024 * 512, v, Mtok, Cc, Cc,
                                                     nullptr, 0, 0, 0);
  xtx<<<dim3(16, 8, 8), 256, 0, stream>>>(xn, Gcov);
  cvt_f32_bf16<<<1024, 256, 0, stream>>>(Gcov, Gcvb, Bb * Cc * Cc);
  // T[b] = Wqk @ Gcov[b]  (Gcov symmetric => @Gcov^T == @Gcov)
  gemm_bt<bf16><<<dim3(4, 8, 8), 256, 0, stream>>>(wq, Gcvb, T, 1024, Cc, Cc,
                                                   nullptr, 0, (long)Cc * Cc, (long)1024 * Cc);
  gram_softmax<<<dim3(Hh, Bb), 256, 0, stream>>>(T, wq, temp, P);
  pv_gelu<<<dim3(8, Hh, Bb), 256, 0, stream>>>(P, v, g);
  // out = g @ proj_w^T + proj_b  (fp32 stores, overwrites v)
  gemm_bt<float><<<dim3(4, 256, 1), 256, 0, stream>>>(g, wp, out, Mtok, Cc, Cc,
                                                      proj_b, 0, 0, 0);
}